// Round 9
// baseline (1595.304 us; speedup 1.0000x reference)
//
#include <hip/hip_runtime.h>

#define BB 128
#define TT 2048
#define HH 64

__device__ __forceinline__ float sigm(float v) {
    return __builtin_amdgcn_rcpf(1.0f + __expf(-v));
}
__device__ __forceinline__ float ftanh(float v) {
    float e = __expf(-2.0f * fabsf(v));
    float r = (1.0f - e) * __builtin_amdgcn_rcpf(1.0f + e);
    return copysignf(r, v);
}

#define PIN4(v) asm volatile("" : "+v"((v).x), "+v"((v).y), "+v"((v).z), "+v"((v).w))
// dot of one float4 weight with one float4 h-slice
#define D4(W, H) ((W).x*(H).x + (W).y*(H).y + (W).z*(H).z + (W).w*(H).w)

// One block per batch, 12 waves. Lane (4g+q) of stage-wave (s,sw) owns
// gate-rows {d, 64+d, 128+d} (d = sw*16+g) x cols [16q,16q+16) of its stage
// matrix = 48 floats/lane. R9 CHANGE vs R8: the 48 floats live in TWELVE
// NAMED float4 variables (w0..w11) instead of a C array. R2-R8 all kept
// weights in arrays; VGPR_Count always < array size (48..132) => the array
// was never SROA-promoted and sat in SCRATCH, so every timestep re-streamed
// 147KB/block from L2 (the flat ~1.6-2.4ms across all structures). Named
// scalars are guaranteed SSA -> the RA finally sees them; launch_bounds
// (768,3) caps VGPR at 170 (truthful occupancy: 12 waves/CU = 3/EU).
// K-quarter partials combine via __shfl_xor(1),(2) in-wave; ONE barrier/iter.
//   s=0: h1(i)  = GRU1(h1(i-1), x(i))          [h1b parity]
//   s=1: xg(i-1)= Wih1*h1(i-1)+bih1            [xgb parity]
//   s=2: h2(i-2)= GRU2(h2(i-3), xg(i-2))       [h2b parity, ring store]
// fc head: wave 7 flushes 64 outputs every 64 iters from the 128-slot ring.
__global__ __launch_bounds__(768, 3)
void gru_fused(const float* __restrict__ x,
               const float* __restrict__ Wih0, const float* __restrict__ Whh0,
               const float* __restrict__ bih0, const float* __restrict__ bhh0,
               const float* __restrict__ Wih1, const float* __restrict__ Whh1,
               const float* __restrict__ bih1, const float* __restrict__ bhh1,
               const float* __restrict__ fcw, const float* __restrict__ fcb,
               float* __restrict__ out)
{
    const int t  = threadIdx.x;
    const int w  = t >> 6;          // wave 0..11
    const int j  = t & 63;          // lane
    const int s  = w >> 2;          // stage 0..2
    const int sw = w & 3;           // dim block
    const int g  = j >> 2;          // local dim 0..15
    const int q  = j & 3;           // K-quarter
    const int d  = sw * 16 + g;     // dim 0..63
    const int b  = blockIdx.x;

    __shared__ __align__(16) float xs[TT * 2];       // 16 KB input
    __shared__ __align__(16) float h1b[2][HH];       // parity
    __shared__ __align__(16) float h2b[2][HH];       // parity
    __shared__ __align__(16) float xgb[2][3 * HH];   // parity
    __shared__ __align__(16) float fwS[HH];
    __shared__ float ring[128][65];                  // h2 history, stride 65

    // ---- 48 resident weight floats: 3 rows x 16 cols, NAMED scalars ----
    const float* Wm = (s == 0) ? Whh0 : (s == 1) ? Wih1 : Whh1;
    const float4* p0 = (const float4*)(Wm + (size_t)(0 * HH + d) * HH + q * 16);
    const float4* p1 = (const float4*)(Wm + (size_t)(1 * HH + d) * HH + q * 16);
    const float4* p2 = (const float4*)(Wm + (size_t)(2 * HH + d) * HH + q * 16);
    float4 w0 = p0[0], w1 = p0[1], w2  = p0[2], w3  = p0[3];
    float4 w4 = p1[0], w5 = p1[1], w6  = p1[2], w7  = p1[3];
    float4 w8 = p2[0], w9 = p2[1], w10 = p2[2], w11 = p2[3];
    PIN4(w0); PIN4(w1); PIN4(w2);  PIN4(w3);
    PIN4(w4); PIN4(w5); PIN4(w6);  PIN4(w7);
    PIN4(w8); PIN4(w9); PIN4(w10); PIN4(w11);

    // biases (added AFTER the shfl combine, so loaded once per lane)
    float kb0, kb1, kb2, bi2 = 0.f;
    if (s == 0) {            // r,z: fold bih0+bhh0; n: bhh0 inside r*(), bih0 outside
        kb0 = bhh0[d] + bih0[d];
        kb1 = bhh0[HH + d] + bih0[HH + d];
        kb2 = bhh0[2 * HH + d];
        bi2 = bih0[2 * HH + d];
    } else if (s == 1) {
        kb0 = bih1[d]; kb1 = bih1[HH + d]; kb2 = bih1[2 * HH + d];
    } else {
        kb0 = bhh1[d]; kb1 = bhh1[HH + d]; kb2 = bhh1[2 * HH + d];
    }
    float wi0 = 0, wi1 = 0, wi2 = 0, wi3 = 0, wi4 = 0, wi5 = 0;
    if (s == 0) {
        wi0 = Wih0[d * 2];            wi1 = Wih0[d * 2 + 1];
        wi2 = Wih0[(HH + d) * 2];     wi3 = Wih0[(HH + d) * 2 + 1];
        wi4 = Wih0[(2 * HH + d) * 2]; wi5 = Wih0[(2 * HH + d) * 2 + 1];
    }
    const float fcbv = fcb[0];

    // ---- preload x, zero state ----
    {
        const float4* xp  = (const float4*)(x + (size_t)b * TT * 2);
        float4*       xsp = (float4*)xs;
        for (int i2 = t; i2 < TT * 2 / 4; i2 += 768) xsp[i2] = xp[i2];
    }
    if (t < 2 * HH) { ((float*)h1b)[t] = 0.f; ((float*)h2b)[t] = 0.f; }
    if (t < HH) fwS[t] = fcw[t];

    float hreg = 0.f;   // s0: h1[d]; s2: h2[d] (tracked redundantly by 4 lanes)

    for (int i = 0; i < TT + 2; ++i) {
        __syncthreads();
        const bool act = (s == 0) ? (i < TT)
                       : (s == 1) ? (i >= 1 && i <= TT)
                                  : (i >= 2);
        if (act) {
            const float4* hp = (const float4*)((s < 2) ? h1b[(i - 1) & 1]
                                                       : h2b[(i - 1) & 1]) + q * 4;
            float4 hA = hp[0], hB = hp[1], hC = hp[2], hD = hp[3];
            float a0 = (D4(w0, hA) + D4(w1, hB)) + (D4(w2,  hC) + D4(w3,  hD));
            float a1 = (D4(w4, hA) + D4(w5, hB)) + (D4(w6,  hC) + D4(w7,  hD));
            float a2 = (D4(w8, hA) + D4(w9, hB)) + (D4(w10, hC) + D4(w11, hD));
            // combine K-quarters in-wave (lanes 4g..4g+3), then biases once
            a0 += __shfl_xor(a0, 1); a0 += __shfl_xor(a0, 2);
            a1 += __shfl_xor(a1, 1); a1 += __shfl_xor(a1, 2);
            a2 += __shfl_xor(a2, 1); a2 += __shfl_xor(a2, 2);
            a0 += kb0; a1 += kb1; a2 += kb2;

            if (s == 0) {                        // layer-1 gates, step i
                float x0 = xs[2 * i], x1 = xs[2 * i + 1];
                float rr = sigm (fmaf(wi0, x0, fmaf(wi1, x1, a0)));
                float zz = sigm (fmaf(wi2, x0, fmaf(wi3, x1, a1)));
                float nn = ftanh(fmaf(wi4, x0, fmaf(wi5, x1, bi2)) + rr * a2);
                hreg = (1.f - zz) * nn + zz * hreg;
                if (q == 0) h1b[i & 1][d] = hreg;
            } else if (s == 1) {                 // xg(i-1) producer
                if (q == 0) {
                    float* xg = xgb[(i - 1) & 1];
                    xg[d] = a0; xg[HH + d] = a1; xg[2 * HH + d] = a2;
                }
            } else {                             // layer-2 gates, step i-2
                const float* xg = xgb[(i - 2) & 1];
                float rr = sigm (xg[d]          + a0);
                float zz = sigm (xg[HH + d]     + a1);
                float nn = ftanh(xg[2 * HH + d] + rr * a2);
                hreg = (1.f - zz) * nn + zz * hreg;
                if (q == 0) {
                    h2b[i & 1][d] = hreg;
                    ring[(i - 2) & 127][d] = hreg;
                }
            }
        }
        // fc-head flush: wave 7, every 64 iters, 64 finished timesteps
        if (w == 7 && i >= 66 && ((i - 66) & 63) == 0) {
            const int tt = ((i - 66) >> 6) * 64 + j;
            const float* rr2 = ring[tt & 127];
            float acc0 = 0.f, acc1 = 0.f;
            #pragma unroll
            for (int k = 0; k < 64; k += 2) {
                acc0 += rr2[k]     * fwS[k];
                acc1 += rr2[k + 1] * fwS[k + 1];
            }
            out[(size_t)b * TT + tt] = acc0 + acc1 + fcbv;
        }
    }
    __syncthreads();
    if (w == 7) {                                // final chunk: t = 1984..2047
        const int tt = 31 * 64 + j;
        const float* rr2 = ring[tt & 127];
        float acc0 = 0.f, acc1 = 0.f;
        #pragma unroll
        for (int k = 0; k < 64; k += 2) {
            acc0 += rr2[k]     * fwS[k];
            acc1 += rr2[k + 1] * fwS[k + 1];
        }
        out[(size_t)b * TT + tt] = acc0 + acc1 + fcbv;
    }
}

extern "C" void kernel_launch(void* const* d_in, const int* in_sizes, int n_in,
                              void* d_out, int out_size, void* d_ws, size_t ws_size,
                              hipStream_t stream) {
    const float* x    = (const float*)d_in[0];
    const float* Wih0 = (const float*)d_in[1];
    const float* Whh0 = (const float*)d_in[2];
    const float* bih0 = (const float*)d_in[3];
    const float* bhh0 = (const float*)d_in[4];
    const float* Wih1 = (const float*)d_in[5];
    const float* Whh1 = (const float*)d_in[6];
    const float* bih1 = (const float*)d_in[7];
    const float* bhh1 = (const float*)d_in[8];
    const float* fcw  = (const float*)d_in[9];
    const float* fcb  = (const float*)d_in[10];
    float* out = (float*)d_out;

    gru_fused<<<BB, 768, 0, stream>>>(x, Wih0, Whh0, bih0, bhh0,
                                      Wih1, Whh1, bih1, bhh1, fcw, fcb, out);
}